// Round 1
// baseline (1211.517 us; speedup 1.0000x reference)
//
#include <hip/hip_runtime.h>

#define N_NODES 100000
#define N_EDGES 1600000
#define IN_F 64
#define HID 128
#define HID2 64
#define NCLS 10

// ---------------- scatter layer 1: agg1 += x[row], deg += 1 ----------------
// one wave (64 lanes) per edge; lane = feature index
__global__ __launch_bounds__(256) void scatter1_k(
    const float* __restrict__ x, const int* __restrict__ row,
    const int* __restrict__ col, float* __restrict__ agg,
    float* __restrict__ deg) {
  int wave = (blockIdx.x * blockDim.x + threadIdx.x) >> 6;
  int lane = threadIdx.x & 63;
  if (wave >= N_EDGES) return;
  int src = row[wave];
  int dst = col[wave];
  float v = x[src * IN_F + lane];
  atomicAdd(&agg[dst * IN_F + lane], v);
  if (lane == 0) atomicAdd(&deg[dst], 1.0f);
}

// ---------------- scatter layer 2: agg2 += h1[row] (128 feats) -------------
__global__ __launch_bounds__(256) void scatter2_k(
    const float* __restrict__ h, const int* __restrict__ row,
    const int* __restrict__ col, float* __restrict__ agg) {
  int wave = (blockIdx.x * blockDim.x + threadIdx.x) >> 6;
  int lane = threadIdx.x & 63;
  if (wave >= N_EDGES) return;
  int src = row[wave];
  int dst = col[wave];
  float v0 = h[src * HID + lane];
  float v1 = h[src * HID + 64 + lane];
  atomicAdd(&agg[dst * HID + lane], v0);
  atomicAdd(&agg[dst * HID + 64 + lane], v1);
}

// ---------------- mm1: h1 = relu((agg1/deg) @ W1 + b1) ---------------------
// 16 nodes per block, W1 (64x128, 32KB) staged in LDS
#define NB1 16
__global__ __launch_bounds__(256) void mm1_k(
    const float* __restrict__ agg, const float* __restrict__ deg,
    const float* __restrict__ W1, const float* __restrict__ b1,
    float* __restrict__ h1) {
  __shared__ float Wl[IN_F * HID];   // 32 KB
  __shared__ float xs[NB1][IN_F];    // 4 KB
  int t = threadIdx.x;
  for (int i = t; i < IN_F * HID; i += 256) Wl[i] = W1[i];
  int node0 = blockIdx.x * NB1;
  for (int i = t; i < NB1 * IN_F; i += 256) {
    int n = i >> 6;
    int k = i & 63;
    int gn = node0 + n;
    float d = deg[gn];
    d = d < 1.0f ? 1.0f : d;
    xs[n][k] = agg[gn * IN_F + k] / d;
  }
  __syncthreads();
  int j = t & 127;   // output column
  int ng = t >> 7;   // node parity group (0/1)
  float acc[8];
#pragma unroll
  for (int i = 0; i < 8; i++) acc[i] = 0.0f;
  for (int k = 0; k < IN_F; k++) {
    float w = Wl[k * HID + j];
#pragma unroll
    for (int i = 0; i < 8; i++) acc[i] += xs[ng + 2 * i][k] * w;
  }
  float bb = b1[j];
#pragma unroll
  for (int i = 0; i < 8; i++) {
    float v = acc[i] + bb;
    v = v > 0.0f ? v : 0.0f;
    h1[(size_t)(node0 + ng + 2 * i) * HID + j] = v;
  }
}

// ------- mm23: out = relu((agg2/deg) @ W2 + b2) @ W3 + b3 (fused) ----------
#define NB2 16
__global__ __launch_bounds__(256) void mm23_k(
    const float* __restrict__ agg2, const float* __restrict__ deg,
    const float* __restrict__ W2, const float* __restrict__ b2,
    const float* __restrict__ W3, const float* __restrict__ b3,
    float* __restrict__ out) {
  __shared__ float W2l[HID * HID2];      // 32 KB
  __shared__ float W3l[HID2 * NCLS];     // 2.5 KB
  __shared__ float xs[NB2][HID];         // 8 KB
  __shared__ float hs[NB2][HID2 + 1];    // 4.06 KB (padded: layer-3 reads stride 65)
  int t = threadIdx.x;
  for (int i = t; i < HID * HID2; i += 256) W2l[i] = W2[i];
  for (int i = t; i < HID2 * NCLS; i += 256) W3l[i] = W3[i];
  int node0 = blockIdx.x * NB2;
  for (int i = t; i < NB2 * HID; i += 256) {
    int n = i >> 7;
    int k = i & 127;
    int gn = node0 + n;
    float d = deg[gn];
    d = d < 1.0f ? 1.0f : d;
    xs[n][k] = agg2[(size_t)gn * HID + k] / d;
  }
  __syncthreads();
  int j = t & 63;    // hidden column
  int ng = t >> 6;   // 0..3
  float acc[4];
#pragma unroll
  for (int i = 0; i < 4; i++) acc[i] = 0.0f;
  for (int k = 0; k < HID; k++) {
    float w = W2l[k * HID2 + j];
#pragma unroll
    for (int i = 0; i < 4; i++) acc[i] += xs[ng + 4 * i][k] * w;
  }
  float bb = b2[j];
#pragma unroll
  for (int i = 0; i < 4; i++) {
    float v = acc[i] + bb;
    hs[ng + 4 * i][j] = v > 0.0f ? v : 0.0f;
  }
  __syncthreads();
  // layer 3: 16 nodes x 10 classes = 160 outputs
  if (t < NB2 * NCLS) {
    int n = t / NCLS;
    int c = t - n * NCLS;
    float a = b3[c];
    for (int k = 0; k < HID2; k++) a += hs[n][k] * W3l[k * NCLS + c];
    out[(size_t)(node0 + n) * NCLS + c] = a;
  }
}

extern "C" void kernel_launch(void* const* d_in, const int* in_sizes, int n_in,
                              void* d_out, int out_size, void* d_ws, size_t ws_size,
                              hipStream_t stream) {
  const float* x  = (const float*)d_in[0];
  const int*   ei = (const int*)d_in[1];
  const int*   row = ei;
  const int*   col = ei + N_EDGES;
  const float* W1 = (const float*)d_in[3];
  const float* b1 = (const float*)d_in[4];
  const float* W2 = (const float*)d_in[5];
  const float* b2 = (const float*)d_in[6];
  const float* W3 = (const float*)d_in[7];
  const float* b3 = (const float*)d_in[8];
  float* out = (float*)d_out;

  char* ws = (char*)d_ws;
  float* deg    = (float*)ws;                          // 0.4 MB (1 MB reserved)
  float* h1     = (float*)(ws + (1 << 20));            // 51.2 MB
  float* aggbuf = h1 + (size_t)N_NODES * HID;          // 51.2 MB (agg1 & agg2)

  // ---- layer 1 ----
  hipMemsetAsync(deg, 0, N_NODES * sizeof(float), stream);
  hipMemsetAsync(aggbuf, 0, (size_t)N_NODES * IN_F * sizeof(float), stream);
  // one wave per edge: E waves = E*64 threads; 256 thr/block -> E/4 blocks
  scatter1_k<<<N_EDGES / 4, 256, 0, stream>>>(x, row, col, aggbuf, deg);
  mm1_k<<<N_NODES / NB1, 256, 0, stream>>>(aggbuf, deg, W1, b1, h1);

  // ---- layer 2 + head ----
  hipMemsetAsync(aggbuf, 0, (size_t)N_NODES * HID * sizeof(float), stream);
  scatter2_k<<<N_EDGES / 4, 256, 0, stream>>>(h1, row, col, aggbuf);
  mm23_k<<<N_NODES / NB2, 256, 0, stream>>>(aggbuf, deg, W2, b2, W3, b3, out);
}

// Round 2
// 704.573 us; speedup vs baseline: 1.7195x; 1.7195x over previous
//
#include <hip/hip_runtime.h>

#define N_NODES 100000
#define N_EDGES 1600000
#define IN_F 64
#define HID 128
#define HID2 64
#define NCLS 10

#define CHUNK 1024
#define NCHUNK ((N_NODES + CHUNK - 1) / CHUNK)   // 98

// ---------------- CSR build ----------------
// counts[dst]++ (int atomics, no write-through penalty like fp)
__global__ __launch_bounds__(256) void count_k(const int* __restrict__ col,
                                               int* __restrict__ counts) {
  int e = blockIdx.x * blockDim.x + threadIdx.x;
  if (e < N_EDGES) atomicAdd(&counts[col[e]], 1);
}

// per-chunk partial sums (chunk = 1024 counts, 256 threads x 4)
__global__ __launch_bounds__(256) void partial_k(const int* __restrict__ counts,
                                                 int* __restrict__ partials) {
  __shared__ int ts[256];
  int base = blockIdx.x * CHUNK + threadIdx.x * 4;
  int s = 0;
#pragma unroll
  for (int i = 0; i < 4; i++) {
    int idx = base + i;
    s += (idx < N_NODES) ? counts[idx] : 0;
  }
  ts[threadIdx.x] = s;
  __syncthreads();
  for (int off = 128; off > 0; off >>= 1) {
    if (threadIdx.x < off) ts[threadIdx.x] += ts[threadIdx.x + off];
    __syncthreads();
  }
  if (threadIdx.x == 0) partials[blockIdx.x] = ts[0];
}

// exclusive scan of the 98 partials (single thread - trivial size)
__global__ void scanp_k(const int* __restrict__ partials, int* __restrict__ pbase) {
  int run = 0;
  for (int i = 0; i < NCHUNK; i++) {
    pbase[i] = run;
    run += partials[i];
  }
}

// rowptr[i] = pbase[chunk] + exclusive_scan_within_chunk(counts)
__global__ __launch_bounds__(256) void rowptr_k(const int* __restrict__ counts,
                                                const int* __restrict__ pbase,
                                                int* __restrict__ rowptr) {
  __shared__ int ts[256];
  int t = threadIdx.x;
  int base = blockIdx.x * CHUNK + t * 4;
  int c[4];
  int s = 0;
#pragma unroll
  for (int i = 0; i < 4; i++) {
    int idx = base + i;
    int v = (idx < N_NODES) ? counts[idx] : 0;
    c[i] = s;         // exclusive within thread
    s += v;
  }
  ts[t] = s;
  __syncthreads();
  // Hillis-Steele inclusive scan of thread sums
  for (int off = 1; off < 256; off <<= 1) {
    int v = (t >= off) ? ts[t - off] : 0;
    __syncthreads();
    ts[t] += v;
    __syncthreads();
  }
  int texcl = ts[t] - s;  // exclusive
  int b = pbase[blockIdx.x];
#pragma unroll
  for (int i = 0; i < 4; i++) {
    int idx = base + i;
    if (idx < N_NODES) rowptr[idx] = b + texcl + c[i];
  }
  if (blockIdx.x == 0 && t == 0) rowptr[N_NODES] = N_EDGES;
}

// scatter edge sources into CSR slots
__global__ __launch_bounds__(256) void fill_k(const int* __restrict__ row,
                                              const int* __restrict__ col,
                                              int* __restrict__ fillptr,
                                              int* __restrict__ csr_src) {
  int e = blockIdx.x * blockDim.x + threadIdx.x;
  if (e < N_EDGES) {
    int pos = atomicAdd(&fillptr[col[e]], 1);
    csr_src[pos] = row[e];
  }
}

// ---------- layer 1 fused: gather x + mm1 -> h1 = relu((agg/deg)@W1+b1) ----
#define NB1 16
__global__ __launch_bounds__(256) void gmm1_k(
    const float* __restrict__ x, const int* __restrict__ rowptr,
    const int* __restrict__ csr_src, const float* __restrict__ W1,
    const float* __restrict__ b1, float* __restrict__ h1) {
  __shared__ float Wl[IN_F * HID];   // 32 KB
  __shared__ float xs[NB1][IN_F];    // 4 KB
  int t = threadIdx.x;
  for (int i = t; i < IN_F * HID; i += 256) Wl[i] = W1[i];
  int node0 = blockIdx.x * NB1;
  int lane = t & 63;
  int wave = t >> 6;          // 4 waves, 4 nodes each
  for (int i = 0; i < 4; i++) {
    int ln = wave * 4 + i;
    int n = node0 + ln;
    int s = rowptr[n], e2 = rowptr[n + 1];
    float acc = 0.0f;
    for (int p = s; p < e2; p++) {
      int src = csr_src[p];
      acc += x[(size_t)src * IN_F + lane];
    }
    int d = e2 - s;
    float dn = (d < 1) ? 1.0f : (float)d;
    xs[ln][lane] = acc / dn;
  }
  __syncthreads();
  int j = t & 127;   // output column
  int ng = t >> 7;   // 0/1
  float acc[8];
#pragma unroll
  for (int i = 0; i < 8; i++) acc[i] = 0.0f;
  for (int k = 0; k < IN_F; k++) {
    float w = Wl[k * HID + j];
#pragma unroll
    for (int i = 0; i < 8; i++) acc[i] += xs[ng + 2 * i][k] * w;
  }
  float bb = b1[j];
#pragma unroll
  for (int i = 0; i < 8; i++) {
    float v = acc[i] + bb;
    v = v > 0.0f ? v : 0.0f;
    h1[(size_t)(node0 + ng + 2 * i) * HID + j] = v;
  }
}

// ---------- transform-first for layer 2: g = h1 @ W2 (no bias) -------------
#define NB2 16
__global__ __launch_bounds__(256) void mm2_k(
    const float* __restrict__ h1, const float* __restrict__ W2,
    float* __restrict__ g) {
  __shared__ float W2l[HID * HID2];   // 32 KB
  __shared__ float xs[NB2][HID];      // 8 KB
  int t = threadIdx.x;
  for (int i = t; i < HID * HID2; i += 256) W2l[i] = W2[i];
  int node0 = blockIdx.x * NB2;
  for (int i = t; i < NB2 * HID; i += 256) {
    int n = i >> 7;
    int k = i & 127;
    xs[n][k] = h1[(size_t)(node0 + n) * HID + k];
  }
  __syncthreads();
  int j = t & 63;    // output column (HID2)
  int ng = t >> 6;   // 0..3
  float acc[4];
#pragma unroll
  for (int i = 0; i < 4; i++) acc[i] = 0.0f;
  for (int k = 0; k < HID; k++) {
    float w = W2l[k * HID2 + j];
#pragma unroll
    for (int i = 0; i < 4; i++) acc[i] += xs[ng + 4 * i][k] * w;
  }
#pragma unroll
  for (int i = 0; i < 4; i++)
    g[(size_t)(node0 + ng + 4 * i) * HID2 + j] = acc[i];
}

// ---------- layer 2 gather + head: out = relu(agg(g)/deg + b2) @ W3 + b3 ---
__global__ __launch_bounds__(256) void ghead_k(
    const float* __restrict__ g, const int* __restrict__ rowptr,
    const int* __restrict__ csr_src, const float* __restrict__ b2,
    const float* __restrict__ W3, const float* __restrict__ b3,
    float* __restrict__ out) {
  __shared__ float W3l[HID2 * NCLS];     // 2.5 KB
  __shared__ float hs[NB2][HID2 + 1];    // padded
  int t = threadIdx.x;
  for (int i = t; i < HID2 * NCLS; i += 256) W3l[i] = W3[i];
  int node0 = blockIdx.x * NB2;
  int lane = t & 63;
  int wave = t >> 6;
  float bb = b2[lane];
  for (int i = 0; i < 4; i++) {
    int ln = wave * 4 + i;
    int n = node0 + ln;
    int s = rowptr[n], e2 = rowptr[n + 1];
    float acc = 0.0f;
    for (int p = s; p < e2; p++) {
      int src = csr_src[p];
      acc += g[(size_t)src * HID2 + lane];
    }
    int d = e2 - s;
    float dn = (d < 1) ? 1.0f : (float)d;
    float v = acc / dn + bb;
    hs[ln][lane] = v > 0.0f ? v : 0.0f;
  }
  __syncthreads();
  if (t < NB2 * NCLS) {
    int n = t / NCLS;
    int c = t - n * NCLS;
    float a = b3[c];
    for (int k = 0; k < HID2; k++) a += hs[n][k] * W3l[k * NCLS + c];
    out[(size_t)(node0 + n) * NCLS + c] = a;
  }
}

extern "C" void kernel_launch(void* const* d_in, const int* in_sizes, int n_in,
                              void* d_out, int out_size, void* d_ws, size_t ws_size,
                              hipStream_t stream) {
  const float* x  = (const float*)d_in[0];
  const int*   ei = (const int*)d_in[1];
  const int*   row = ei;
  const int*   col = ei + N_EDGES;
  const float* W1 = (const float*)d_in[3];
  const float* b1 = (const float*)d_in[4];
  const float* W2 = (const float*)d_in[5];
  const float* b2 = (const float*)d_in[6];
  const float* W3 = (const float*)d_in[7];
  const float* b3 = (const float*)d_in[8];
  float* out = (float*)d_out;

  char* ws = (char*)d_ws;
  int*   rowptr  = (int*)ws;                            // 512 KB reserved
  int*   fillptr = (int*)(ws + (512 << 10));            // 512 KB (counts, then fill cursors)
  int*   partials= (int*)(ws + (1 << 20));              // 512 B
  int*   pbase   = (int*)(ws + (1 << 20) + 512);        // 512 B
  int*   csr_src = (int*)(ws + (1 << 20) + 4096);       // 6.4 MB
  float* h1      = (float*)(ws + (8 << 20));            // 51.2 MB
  float* g       = h1 + (size_t)N_NODES * HID;          // 25.6 MB

  // ---- CSR build (once, reused by both layers) ----
  hipMemsetAsync(fillptr, 0, N_NODES * sizeof(int), stream);
  count_k<<<(N_EDGES + 255) / 256, 256, 0, stream>>>(col, fillptr);
  partial_k<<<NCHUNK, 256, 0, stream>>>(fillptr, partials);
  scanp_k<<<1, 1, 0, stream>>>(partials, pbase);
  rowptr_k<<<NCHUNK, 256, 0, stream>>>(fillptr, pbase, rowptr);
  hipMemcpyAsync(fillptr, rowptr, N_NODES * sizeof(int),
                 hipMemcpyDeviceToDevice, stream);
  fill_k<<<(N_EDGES + 255) / 256, 256, 0, stream>>>(row, col, fillptr, csr_src);

  // ---- layer 1: gather + mm1 fused ----
  gmm1_k<<<N_NODES / NB1, 256, 0, stream>>>(x, rowptr, csr_src, W1, b1, h1);

  // ---- layer 2: transform-first, then gather + head fused ----
  mm2_k<<<N_NODES / NB2, 256, 0, stream>>>(h1, W2, g);
  ghead_k<<<N_NODES / NB2, 256, 0, stream>>>(g, rowptr, csr_src, b2, W3, b3, out);
}

// Round 3
// 456.902 us; speedup vs baseline: 2.6516x; 1.5421x over previous
//
#include <hip/hip_runtime.h>

#define N_NODES 100000
#define N_EDGES 1600000
#define IN_F 64
#define HID 128
#define HID2 64
#define NCLS 10

#define CHUNK 1024
#define NCHUNK ((N_NODES + CHUNK - 1) / CHUNK)   // 98

// ---------------- CSR build ----------------
__global__ __launch_bounds__(256) void count_k(const int* __restrict__ col,
                                               int* __restrict__ counts) {
  int e = blockIdx.x * blockDim.x + threadIdx.x;
  if (e < N_EDGES) atomicAdd(&counts[col[e]], 1);
}

__global__ __launch_bounds__(256) void partial_k(const int* __restrict__ counts,
                                                 int* __restrict__ partials) {
  __shared__ int ts[256];
  int base = blockIdx.x * CHUNK + threadIdx.x * 4;
  int s = 0;
#pragma unroll
  for (int i = 0; i < 4; i++) {
    int idx = base + i;
    s += (idx < N_NODES) ? counts[idx] : 0;
  }
  ts[threadIdx.x] = s;
  __syncthreads();
  for (int off = 128; off > 0; off >>= 1) {
    if (threadIdx.x < off) ts[threadIdx.x] += ts[threadIdx.x + off];
    __syncthreads();
  }
  if (threadIdx.x == 0) partials[blockIdx.x] = ts[0];
}

__global__ void scanp_k(const int* __restrict__ partials, int* __restrict__ pbase) {
  int run = 0;
  for (int i = 0; i < NCHUNK; i++) {
    pbase[i] = run;
    run += partials[i];
  }
}

__global__ __launch_bounds__(256) void rowptr_k(const int* __restrict__ counts,
                                                const int* __restrict__ pbase,
                                                int* __restrict__ rowptr) {
  __shared__ int ts[256];
  int t = threadIdx.x;
  int base = blockIdx.x * CHUNK + t * 4;
  int c[4];
  int s = 0;
#pragma unroll
  for (int i = 0; i < 4; i++) {
    int idx = base + i;
    int v = (idx < N_NODES) ? counts[idx] : 0;
    c[i] = s;
    s += v;
  }
  ts[t] = s;
  __syncthreads();
  for (int off = 1; off < 256; off <<= 1) {
    int v = (t >= off) ? ts[t - off] : 0;
    __syncthreads();
    ts[t] += v;
    __syncthreads();
  }
  int texcl = ts[t] - s;
  int b = pbase[blockIdx.x];
#pragma unroll
  for (int i = 0; i < 4; i++) {
    int idx = base + i;
    if (idx < N_NODES) rowptr[idx] = b + texcl + c[i];
  }
  if (blockIdx.x == 0 && t == 0) rowptr[N_NODES] = N_EDGES;
}

__global__ __launch_bounds__(256) void fill_k(const int* __restrict__ row,
                                              const int* __restrict__ col,
                                              int* __restrict__ fillptr,
                                              int* __restrict__ csr_src) {
  int e = blockIdx.x * blockDim.x + threadIdx.x;
  if (e < N_EDGES) {
    int pos = atomicAdd(&fillptr[col[e]], 1);
    csr_src[pos] = row[e];
  }
}

// ---------- ILP-4 predicated segment gather (64-wide rows) ----------
// returns sum over [s,e2) of src[csr[p]*64 + lane]; 4 loads in flight
__device__ __forceinline__ float gather64_ilp4(const float* __restrict__ v,
                                               const int* __restrict__ csr_src,
                                               int s, int e2, int lane) {
  float acc = 0.0f;
  int last = e2 - 1;
  for (int p = s; p < e2; p += 4) {
    int p1 = p + 1 <= last ? p + 1 : last;
    int p2 = p + 2 <= last ? p + 2 : last;
    int p3 = p + 3 <= last ? p + 3 : last;
    int s0 = csr_src[p];
    int s1 = csr_src[p1];
    int s2 = csr_src[p2];
    int s3 = csr_src[p3];
    float v0 = v[s0 * 64 + lane];
    float v1 = v[s1 * 64 + lane];
    float v2 = v[s2 * 64 + lane];
    float v3 = v[s3 * 64 + lane];
    acc += v0;
    acc += (p + 1 <= last) ? v1 : 0.0f;
    acc += (p + 2 <= last) ? v2 : 0.0f;
    acc += (p + 3 <= last) ? v3 : 0.0f;
  }
  return acc;
}

// ---------- layer 1 fused: gather x + mm1 -> h1 = relu((agg/deg)@W1+b1) ----
#define NB1 16
__global__ __launch_bounds__(256) void gmm1_k(
    const float* __restrict__ x, const int* __restrict__ rowptr,
    const int* __restrict__ csr_src, const float* __restrict__ W1,
    const float* __restrict__ b1, float* __restrict__ h1) {
  __shared__ float Wl[IN_F * HID];   // 32 KB
  __shared__ float xs[NB1][IN_F];    // 4 KB
  int t = threadIdx.x;
  for (int i = t; i < IN_F * HID; i += 256) Wl[i] = W1[i];
  int node0 = blockIdx.x * NB1;
  int lane = t & 63;
  int wave = t >> 6;          // 4 waves, 4 nodes each
  for (int i = 0; i < 4; i++) {
    int ln = wave * 4 + i;
    int n = node0 + ln;
    int s = rowptr[n], e2 = rowptr[n + 1];
    float acc = gather64_ilp4(x, csr_src, s, e2, lane);
    int d = e2 - s;
    float dn = (d < 1) ? 1.0f : (float)d;
    xs[ln][lane] = acc / dn;
  }
  __syncthreads();
  int j = t & 127;   // output column
  int ng = t >> 7;   // 0/1
  float acc[8];
#pragma unroll
  for (int i = 0; i < 8; i++) acc[i] = 0.0f;
  for (int k = 0; k < IN_F; k++) {
    float w = Wl[k * HID + j];
#pragma unroll
    for (int i = 0; i < 8; i++) acc[i] += xs[ng + 2 * i][k] * w;
  }
  float bb = b1[j];
#pragma unroll
  for (int i = 0; i < 8; i++) {
    float v = acc[i] + bb;
    v = v > 0.0f ? v : 0.0f;
    h1[(node0 + ng + 2 * i) * HID + j] = v;
  }
}

// ---------- transform-first for layer 2: g = h1 @ W2 (no bias) -------------
#define NB2 16
__global__ __launch_bounds__(256) void mm2_k(
    const float* __restrict__ h1, const float* __restrict__ W2,
    float* __restrict__ g) {
  __shared__ float W2l[HID * HID2];   // 32 KB
  __shared__ float xs[NB2][HID];      // 8 KB
  int t = threadIdx.x;
  for (int i = t; i < HID * HID2; i += 256) W2l[i] = W2[i];
  int node0 = blockIdx.x * NB2;
  for (int i = t; i < NB2 * HID; i += 256) {
    int n = i >> 7;
    int k = i & 127;
    xs[n][k] = h1[(node0 + n) * HID + k];
  }
  __syncthreads();
  int j = t & 63;    // output column (HID2)
  int ng = t >> 6;   // 0..3
  float acc[4];
#pragma unroll
  for (int i = 0; i < 4; i++) acc[i] = 0.0f;
  for (int k = 0; k < HID; k++) {
    float w = W2l[k * HID2 + j];
#pragma unroll
    for (int i = 0; i < 4; i++) acc[i] += xs[ng + 4 * i][k] * w;
  }
#pragma unroll
  for (int i = 0; i < 4; i++)
    g[(node0 + ng + 4 * i) * HID2 + j] = acc[i];
}

// ---------- layer 2 gather + head: out = relu(agg(g)/deg + b2) @ W3 + b3 ---
__global__ __launch_bounds__(256) void ghead_k(
    const float* __restrict__ g, const int* __restrict__ rowptr,
    const int* __restrict__ csr_src, const float* __restrict__ b2,
    const float* __restrict__ W3, const float* __restrict__ b3,
    float* __restrict__ out) {
  __shared__ float W3l[HID2 * NCLS];     // 2.5 KB
  __shared__ float hs[NB2][HID2 + 1];    // padded
  int t = threadIdx.x;
  for (int i = t; i < HID2 * NCLS; i += 256) W3l[i] = W3[i];
  int node0 = blockIdx.x * NB2;
  int lane = t & 63;
  int wave = t >> 6;
  float bb = b2[lane];
  for (int i = 0; i < 4; i++) {
    int ln = wave * 4 + i;
    int n = node0 + ln;
    int s = rowptr[n], e2 = rowptr[n + 1];
    float acc = gather64_ilp4(g, csr_src, s, e2, lane);
    int d = e2 - s;
    float dn = (d < 1) ? 1.0f : (float)d;
    float v = acc / dn + bb;
    hs[ln][lane] = v > 0.0f ? v : 0.0f;
  }
  __syncthreads();
  if (t < NB2 * NCLS) {
    int n = t / NCLS;
    int c = t - n * NCLS;
    float a = b3[c];
    for (int k = 0; k < HID2; k++) a += hs[n][k] * W3l[k * NCLS + c];
    out[(node0 + n) * NCLS + c] = a;
  }
}

extern "C" void kernel_launch(void* const* d_in, const int* in_sizes, int n_in,
                              void* d_out, int out_size, void* d_ws, size_t ws_size,
                              hipStream_t stream) {
  const float* x  = (const float*)d_in[0];
  const int*   ei = (const int*)d_in[1];
  const int*   row = ei;
  const int*   col = ei + N_EDGES;
  const float* W1 = (const float*)d_in[3];
  const float* b1 = (const float*)d_in[4];
  const float* W2 = (const float*)d_in[5];
  const float* b2 = (const float*)d_in[6];
  const float* W3 = (const float*)d_in[7];
  const float* b3 = (const float*)d_in[8];
  float* out = (float*)d_out;

  char* ws = (char*)d_ws;
  int*   rowptr  = (int*)ws;                            // 512 KB reserved
  int*   fillptr = (int*)(ws + (512 << 10));            // counts, then fill cursors
  int*   partials= (int*)(ws + (1 << 20));
  int*   pbase   = (int*)(ws + (1 << 20) + 512);
  int*   csr_src = (int*)(ws + (1 << 20) + 4096);       // 6.4 MB
  float* h1      = (float*)(ws + (8 << 20));            // 51.2 MB
  float* g       = h1 + (size_t)N_NODES * HID;          // 25.6 MB

  // ---- CSR build (once, reused by both layers) ----
  hipMemsetAsync(fillptr, 0, N_NODES * sizeof(int), stream);
  count_k<<<(N_EDGES + 255) / 256, 256, 0, stream>>>(col, fillptr);
  partial_k<<<NCHUNK, 256, 0, stream>>>(fillptr, partials);
  scanp_k<<<1, 1, 0, stream>>>(partials, pbase);
  rowptr_k<<<NCHUNK, 256, 0, stream>>>(fillptr, pbase, rowptr);
  hipMemcpyAsync(fillptr, rowptr, N_NODES * sizeof(int),
                 hipMemcpyDeviceToDevice, stream);
  fill_k<<<(N_EDGES + 255) / 256, 256, 0, stream>>>(row, col, fillptr, csr_src);

  // ---- layer 1: gather + mm1 fused ----
  gmm1_k<<<N_NODES / NB1, 256, 0, stream>>>(x, rowptr, csr_src, W1, b1, h1);

  // ---- layer 2: transform-first, then gather + head fused ----
  mm2_k<<<N_NODES / NB2, 256, 0, stream>>>(h1, W2, g);
  ghead_k<<<N_NODES / NB2, 256, 0, stream>>>(g, rowptr, csr_src, b2, W3, b3, out);
}

// Round 4
// 404.352 us; speedup vs baseline: 2.9962x; 1.1300x over previous
//
#include <hip/hip_runtime.h>

#define N_NODES 100000
#define N_EDGES 1600000
#define IN_F 64
#define HID 128
#define HID2 64
#define NCLS 10

#define CHUNK 1024
#define NCHUNK ((N_NODES + CHUNK - 1) / CHUNK)   // 98

// ---------------- CSR build ----------------
__global__ __launch_bounds__(256) void count_k(const int* __restrict__ col,
                                               int* __restrict__ counts) {
  int e = blockIdx.x * blockDim.x + threadIdx.x;
  if (e < N_EDGES) atomicAdd(&counts[col[e]], 1);
}

__global__ __launch_bounds__(256) void partial_k(const int* __restrict__ counts,
                                                 int* __restrict__ partials) {
  __shared__ int ts[256];
  int base = blockIdx.x * CHUNK + threadIdx.x * 4;
  int s = 0;
#pragma unroll
  for (int i = 0; i < 4; i++) {
    int idx = base + i;
    s += (idx < N_NODES) ? counts[idx] : 0;
  }
  ts[threadIdx.x] = s;
  __syncthreads();
  for (int off = 128; off > 0; off >>= 1) {
    if (threadIdx.x < off) ts[threadIdx.x] += ts[threadIdx.x + off];
    __syncthreads();
  }
  if (threadIdx.x == 0) partials[blockIdx.x] = ts[0];
}

__global__ void scanp_k(const int* __restrict__ partials, int* __restrict__ pbase) {
  int run = 0;
  for (int i = 0; i < NCHUNK; i++) {
    pbase[i] = run;
    run += partials[i];
  }
}

__global__ __launch_bounds__(256) void rowptr_k(const int* __restrict__ counts,
                                                const int* __restrict__ pbase,
                                                int* __restrict__ rowptr) {
  __shared__ int ts[256];
  int t = threadIdx.x;
  int base = blockIdx.x * CHUNK + t * 4;
  int c[4];
  int s = 0;
#pragma unroll
  for (int i = 0; i < 4; i++) {
    int idx = base + i;
    int v = (idx < N_NODES) ? counts[idx] : 0;
    c[i] = s;
    s += v;
  }
  ts[t] = s;
  __syncthreads();
  for (int off = 1; off < 256; off <<= 1) {
    int v = (t >= off) ? ts[t - off] : 0;
    __syncthreads();
    ts[t] += v;
    __syncthreads();
  }
  int texcl = ts[t] - s;
  int b = pbase[blockIdx.x];
#pragma unroll
  for (int i = 0; i < 4; i++) {
    int idx = base + i;
    if (idx < N_NODES) rowptr[idx] = b + texcl + c[i];
  }
  if (blockIdx.x == 0 && t == 0) rowptr[N_NODES] = N_EDGES;
}

__global__ __launch_bounds__(256) void fill_k(const int* __restrict__ row,
                                              const int* __restrict__ col,
                                              int* __restrict__ fillptr,
                                              int* __restrict__ csr_src) {
  int e = blockIdx.x * blockDim.x + threadIdx.x;
  if (e < N_EDGES) {
    int pos = atomicAdd(&fillptr[col[e]], 1);
    csr_src[pos] = row[e];
  }
}

// ---------- wave gather: 4 edges x 16 float4-chunks per load round ----------
// lane = eg(=lane>>4) edge subgroup, fc(=lane&15) feature chunk.
// Each iteration covers 16 edges (unroll 4 x 4 subgroups), 4KB in flight/wave.
// Afterwards all lanes hold the segment sum for chunk fc (xor-reduce 16,32).
__device__ __forceinline__ float4 gatherrow_f4(const float4* __restrict__ vf4,
                                               const int* __restrict__ csr_src,
                                               int s, int e2, int eg, int fc) {
  float4 acc = make_float4(0.0f, 0.0f, 0.0f, 0.0f);
  for (int p = s; p < e2; p += 16) {
#pragma unroll
    for (int u = 0; u < 4; u++) {
      int e = p + 4 * u + eg;
      int ec = e < e2 ? e : e2 - 1;
      int src = csr_src[ec];
      float4 v = vf4[(size_t)src * 16 + fc];
      bool ok = e < e2;
      acc.x += ok ? v.x : 0.0f;
      acc.y += ok ? v.y : 0.0f;
      acc.z += ok ? v.z : 0.0f;
      acc.w += ok ? v.w : 0.0f;
    }
  }
  acc.x += __shfl_xor(acc.x, 16);
  acc.y += __shfl_xor(acc.y, 16);
  acc.z += __shfl_xor(acc.z, 16);
  acc.w += __shfl_xor(acc.w, 16);
  acc.x += __shfl_xor(acc.x, 32);
  acc.y += __shfl_xor(acc.y, 32);
  acc.z += __shfl_xor(acc.z, 32);
  acc.w += __shfl_xor(acc.w, 32);
  return acc;
}

// ---------- layer 1 fused: gather x + mm1 -> h1 = relu((agg/deg)@W1+b1) ----
#define NB1 16
__global__ __launch_bounds__(256) void gmm1_k(
    const float* __restrict__ x, const int* __restrict__ rowptr,
    const int* __restrict__ csr_src, const float* __restrict__ W1,
    const float* __restrict__ b1, float* __restrict__ h1) {
  __shared__ float Wl[IN_F * HID];   // 32 KB
  __shared__ float xs[NB1][IN_F];    // 4 KB
  int t = threadIdx.x;
  for (int i = t; i < IN_F * HID; i += 256) Wl[i] = W1[i];
  int node0 = blockIdx.x * NB1;
  int lane = t & 63;
  int wave = t >> 6;          // 4 waves, 4 nodes each
  int eg = lane >> 4;
  int fc = lane & 15;
  const float4* xf4 = (const float4*)x;
  for (int i = 0; i < 4; i++) {
    int ln = wave * 4 + i;
    int n = node0 + ln;
    int s = rowptr[n], e2 = rowptr[n + 1];
    float4 a = gatherrow_f4(xf4, csr_src, s, e2, eg, fc);
    int d = e2 - s;
    float inv = 1.0f / (d < 1 ? 1.0f : (float)d);
    if (eg == 0) {
      float4 w;
      w.x = a.x * inv; w.y = a.y * inv; w.z = a.z * inv; w.w = a.w * inv;
      *(float4*)&xs[ln][fc * 4] = w;
    }
  }
  __syncthreads();
  int j = t & 127;   // output column
  int ng = t >> 7;   // 0/1
  float acc[8];
#pragma unroll
  for (int i = 0; i < 8; i++) acc[i] = 0.0f;
  for (int k = 0; k < IN_F; k++) {
    float w = Wl[k * HID + j];
#pragma unroll
    for (int i = 0; i < 8; i++) acc[i] += xs[ng + 2 * i][k] * w;
  }
  float bb = b1[j];
#pragma unroll
  for (int i = 0; i < 8; i++) {
    float v = acc[i] + bb;
    v = v > 0.0f ? v : 0.0f;
    h1[(node0 + ng + 2 * i) * HID + j] = v;
  }
}

// ---------- transform-first for layer 2: g = h1 @ W2 (no bias) -------------
#define NB2 16
__global__ __launch_bounds__(256) void mm2_k(
    const float* __restrict__ h1, const float* __restrict__ W2,
    float* __restrict__ g) {
  __shared__ float W2l[HID * HID2];   // 32 KB
  __shared__ float xs[NB2][HID];      // 8 KB
  int t = threadIdx.x;
  for (int i = t; i < HID * HID2; i += 256) W2l[i] = W2[i];
  int node0 = blockIdx.x * NB2;
  for (int i = t; i < NB2 * HID; i += 256) {
    int n = i >> 7;
    int k = i & 127;
    xs[n][k] = h1[(node0 + n) * HID + k];
  }
  __syncthreads();
  int j = t & 63;    // output column (HID2)
  int ng = t >> 6;   // 0..3
  float acc[4];
#pragma unroll
  for (int i = 0; i < 4; i++) acc[i] = 0.0f;
  for (int k = 0; k < HID; k++) {
    float w = W2l[k * HID2 + j];
#pragma unroll
    for (int i = 0; i < 4; i++) acc[i] += xs[ng + 4 * i][k] * w;
  }
#pragma unroll
  for (int i = 0; i < 4; i++)
    g[(node0 + ng + 4 * i) * HID2 + j] = acc[i];
}

// ---------- layer 2 gather + head: out = relu(agg(g)/deg + b2) @ W3 + b3 ---
__global__ __launch_bounds__(256) void ghead_k(
    const float* __restrict__ g, const int* __restrict__ rowptr,
    const int* __restrict__ csr_src, const float* __restrict__ b2,
    const float* __restrict__ W3, const float* __restrict__ b3,
    float* __restrict__ out) {
  __shared__ float W3l[HID2 * NCLS];     // 2.5 KB
  __shared__ float hs[NB2][HID2 + 4];    // +4 keeps 16B alignment for float4
  int t = threadIdx.x;
  for (int i = t; i < HID2 * NCLS; i += 256) W3l[i] = W3[i];
  int node0 = blockIdx.x * NB2;
  int lane = t & 63;
  int wave = t >> 6;
  int eg = lane >> 4;
  int fc = lane & 15;
  const float4* gf4 = (const float4*)g;
  const float4* b2f4 = (const float4*)b2;
  for (int i = 0; i < 4; i++) {
    int ln = wave * 4 + i;
    int n = node0 + ln;
    int s = rowptr[n], e2 = rowptr[n + 1];
    float4 a = gatherrow_f4(gf4, csr_src, s, e2, eg, fc);
    int d = e2 - s;
    float inv = 1.0f / (d < 1 ? 1.0f : (float)d);
    if (eg == 0) {
      float4 bb = b2f4[fc];
      float4 v;
      v.x = a.x * inv + bb.x; v.y = a.y * inv + bb.y;
      v.z = a.z * inv + bb.z; v.w = a.w * inv + bb.w;
      v.x = v.x > 0.0f ? v.x : 0.0f;
      v.y = v.y > 0.0f ? v.y : 0.0f;
      v.z = v.z > 0.0f ? v.z : 0.0f;
      v.w = v.w > 0.0f ? v.w : 0.0f;
      *(float4*)&hs[ln][fc * 4] = v;
    }
  }
  __syncthreads();
  if (t < NB2 * NCLS) {
    int n = t / NCLS;
    int c = t - n * NCLS;
    float a = b3[c];
    for (int k = 0; k < HID2; k++) a += hs[n][k] * W3l[k * NCLS + c];
    out[(node0 + n) * NCLS + c] = a;
  }
}

extern "C" void kernel_launch(void* const* d_in, const int* in_sizes, int n_in,
                              void* d_out, int out_size, void* d_ws, size_t ws_size,
                              hipStream_t stream) {
  const float* x  = (const float*)d_in[0];
  const int*   ei = (const int*)d_in[1];
  const int*   row = ei;
  const int*   col = ei + N_EDGES;
  const float* W1 = (const float*)d_in[3];
  const float* b1 = (const float*)d_in[4];
  const float* W2 = (const float*)d_in[5];
  const float* b2 = (const float*)d_in[6];
  const float* W3 = (const float*)d_in[7];
  const float* b3 = (const float*)d_in[8];
  float* out = (float*)d_out;

  char* ws = (char*)d_ws;
  int*   rowptr  = (int*)ws;                            // 512 KB reserved
  int*   fillptr = (int*)(ws + (512 << 10));            // counts, then fill cursors
  int*   partials= (int*)(ws + (1 << 20));
  int*   pbase   = (int*)(ws + (1 << 20) + 512);
  int*   csr_src = (int*)(ws + (1 << 20) + 4096);       // 6.4 MB
  float* h1      = (float*)(ws + (8 << 20));            // 51.2 MB
  float* g       = h1 + (size_t)N_NODES * HID;          // 25.6 MB

  // ---- CSR build (once, reused by both layers) ----
  hipMemsetAsync(fillptr, 0, N_NODES * sizeof(int), stream);
  count_k<<<(N_EDGES + 255) / 256, 256, 0, stream>>>(col, fillptr);
  partial_k<<<NCHUNK, 256, 0, stream>>>(fillptr, partials);
  scanp_k<<<1, 1, 0, stream>>>(partials, pbase);
  rowptr_k<<<NCHUNK, 256, 0, stream>>>(fillptr, pbase, rowptr);
  hipMemcpyAsync(fillptr, rowptr, N_NODES * sizeof(int),
                 hipMemcpyDeviceToDevice, stream);
  fill_k<<<(N_EDGES + 255) / 256, 256, 0, stream>>>(row, col, fillptr, csr_src);

  // ---- layer 1: gather + mm1 fused ----
  gmm1_k<<<N_NODES / NB1, 256, 0, stream>>>(x, rowptr, csr_src, W1, b1, h1);

  // ---- layer 2: transform-first, then gather + head fused ----
  mm2_k<<<N_NODES / NB2, 256, 0, stream>>>(h1, W2, g);
  ghead_k<<<N_NODES / NB2, 256, 0, stream>>>(g, rowptr, csr_src, b2, W3, b3, out);
}

// Round 5
// 340.659 us; speedup vs baseline: 3.5564x; 1.1870x over previous
//
#include <hip/hip_runtime.h>

#define N_NODES 100000
#define N_EDGES 1600000
#define IN_F 64
#define HID 128
#define HID2 64
#define NCLS 10

#define CHUNK 1024
#define NCHUNK ((N_NODES + CHUNK - 1) / CHUNK)   // 98

// XCD-local CSR build: 8 dst-ranges x 128 edge-chunks
#define NRANGE 8
#define RANGE_NODES ((N_NODES + NRANGE - 1) / NRANGE)   // 12500
#define EBLK 128
#define ECHUNK (N_EDGES / EBLK)                          // 12500

// ---------------- CSR build (XCD-local) ----------------
// block b: dst-range r=b%8 (lands on XCD r under round-robin dispatch),
// edge-chunk j=b/8. Atomics+scatter stay in one XCD's L2 slice.
__global__ __launch_bounds__(256) void count2_k(const int* __restrict__ col,
                                                int* __restrict__ counts) {
  int r = blockIdx.x & (NRANGE - 1);
  int j = blockIdx.x >> 3;
  int lo = r * RANGE_NODES, hi = lo + RANGE_NODES;
  int e0 = j * ECHUNK, e1 = e0 + ECHUNK;
  for (int e = e0 + threadIdx.x; e < e1; e += 256) {
    int dst = col[e];
    if (dst >= lo && dst < hi) atomicAdd(&counts[dst], 1);
  }
}

__global__ __launch_bounds__(256) void fill2_k(const int* __restrict__ row,
                                               const int* __restrict__ col,
                                               int* __restrict__ fillptr,
                                               int* __restrict__ csr_src) {
  int r = blockIdx.x & (NRANGE - 1);
  int j = blockIdx.x >> 3;
  int lo = r * RANGE_NODES, hi = lo + RANGE_NODES;
  int e0 = j * ECHUNK, e1 = e0 + ECHUNK;
  for (int e = e0 + threadIdx.x; e < e1; e += 256) {
    int dst = col[e];
    int src = row[e];
    if (dst >= lo && dst < hi) {
      int pos = atomicAdd(&fillptr[dst], 1);
      csr_src[pos] = src;
    }
  }
}

__global__ __launch_bounds__(256) void partial_k(const int* __restrict__ counts,
                                                 int* __restrict__ partials) {
  __shared__ int ts[256];
  int base = blockIdx.x * CHUNK + threadIdx.x * 4;
  int s = 0;
#pragma unroll
  for (int i = 0; i < 4; i++) {
    int idx = base + i;
    s += (idx < N_NODES) ? counts[idx] : 0;
  }
  ts[threadIdx.x] = s;
  __syncthreads();
  for (int off = 128; off > 0; off >>= 1) {
    if (threadIdx.x < off) ts[threadIdx.x] += ts[threadIdx.x + off];
    __syncthreads();
  }
  if (threadIdx.x == 0) partials[blockIdx.x] = ts[0];
}

__global__ void scanp_k(const int* __restrict__ partials, int* __restrict__ pbase) {
  int run = 0;
  for (int i = 0; i < NCHUNK; i++) {
    pbase[i] = run;
    run += partials[i];
  }
}

__global__ __launch_bounds__(256) void rowptr_k(const int* __restrict__ counts,
                                                const int* __restrict__ pbase,
                                                int* __restrict__ rowptr) {
  __shared__ int ts[256];
  int t = threadIdx.x;
  int base = blockIdx.x * CHUNK + t * 4;
  int c[4];
  int s = 0;
#pragma unroll
  for (int i = 0; i < 4; i++) {
    int idx = base + i;
    int v = (idx < N_NODES) ? counts[idx] : 0;
    c[i] = s;
    s += v;
  }
  ts[t] = s;
  __syncthreads();
  for (int off = 1; off < 256; off <<= 1) {
    int v = (t >= off) ? ts[t - off] : 0;
    __syncthreads();
    ts[t] += v;
    __syncthreads();
  }
  int texcl = ts[t] - s;
  int b = pbase[blockIdx.x];
#pragma unroll
  for (int i = 0; i < 4; i++) {
    int idx = base + i;
    if (idx < N_NODES) rowptr[idx] = b + texcl + c[i];
  }
  if (blockIdx.x == 0 && t == 0) rowptr[N_NODES] = N_EDGES;
}

// ---------- wave gather: lane = eg(edge subgroup, 4) x fc(feature f4, 16) ---
// Hot path: first 32 edges as a predicated straight-line (8 independent f4
// loads in flight); rare residual loop for degree > 32 (P ~ 1e-4 @ mean 16).
// Finish with xor-reduce 16,32 so all lanes hold the chunk-fc segment sum.
__device__ __forceinline__ float4 gatherrow_f4(const float4* __restrict__ vf4,
                                               const int* __restrict__ csr_src,
                                               int s, int e2, int eg, int fc) {
  float4 acc = make_float4(0.0f, 0.0f, 0.0f, 0.0f);
  if (s < e2) {
    int last = e2 - 1;
#pragma unroll
    for (int u = 0; u < 8; u++) {
      int e = s + 4 * u + eg;
      int ec = e <= last ? e : last;
      int src = csr_src[ec];
      float4 v = vf4[(size_t)src * 16 + fc];
      bool ok = e <= last;
      acc.x += ok ? v.x : 0.0f;
      acc.y += ok ? v.y : 0.0f;
      acc.z += ok ? v.z : 0.0f;
      acc.w += ok ? v.w : 0.0f;
    }
    for (int p = s + 32; p < e2; p += 16) {
#pragma unroll
      for (int u = 0; u < 4; u++) {
        int e = p + 4 * u + eg;
        int ec = e <= last ? e : last;
        int src = csr_src[ec];
        float4 v = vf4[(size_t)src * 16 + fc];
        bool ok = e <= last;
        acc.x += ok ? v.x : 0.0f;
        acc.y += ok ? v.y : 0.0f;
        acc.z += ok ? v.z : 0.0f;
        acc.w += ok ? v.w : 0.0f;
      }
    }
  }
  acc.x += __shfl_xor(acc.x, 16);
  acc.y += __shfl_xor(acc.y, 16);
  acc.z += __shfl_xor(acc.z, 16);
  acc.w += __shfl_xor(acc.w, 16);
  acc.x += __shfl_xor(acc.x, 32);
  acc.y += __shfl_xor(acc.y, 32);
  acc.z += __shfl_xor(acc.z, 32);
  acc.w += __shfl_xor(acc.w, 32);
  return acc;
}

// ---------- layer 1 fused: gather x + mm1 -> h1 = relu((agg/deg)@W1+b1) ----
#define NB1 16
__global__ __launch_bounds__(256) void gmm1_k(
    const float* __restrict__ x, const int* __restrict__ rowptr,
    const int* __restrict__ csr_src, const float* __restrict__ W1,
    const float* __restrict__ b1, float* __restrict__ h1) {
  __shared__ float Wl[IN_F * HID];   // 32 KB
  __shared__ float xs[NB1][IN_F];    // 4 KB
  int t = threadIdx.x;
  for (int i = t; i < IN_F * HID; i += 256) Wl[i] = W1[i];
  int node0 = blockIdx.x * NB1;
  int lane = t & 63;
  int wave = t >> 6;          // 4 waves, 4 nodes each
  int eg = lane >> 4;
  int fc = lane & 15;
  const float4* xf4 = (const float4*)x;
  for (int i = 0; i < 4; i++) {
    int ln = wave * 4 + i;
    int n = node0 + ln;
    int s = rowptr[n], e2 = rowptr[n + 1];
    float4 a = gatherrow_f4(xf4, csr_src, s, e2, eg, fc);
    int d = e2 - s;
    float inv = 1.0f / (d < 1 ? 1.0f : (float)d);
    if (eg == 0) {
      float4 w;
      w.x = a.x * inv; w.y = a.y * inv; w.z = a.z * inv; w.w = a.w * inv;
      *(float4*)&xs[ln][fc * 4] = w;
    }
  }
  __syncthreads();
  int j = t & 127;   // output column
  int ng = t >> 7;   // 0/1
  float acc[8];
#pragma unroll
  for (int i = 0; i < 8; i++) acc[i] = 0.0f;
  for (int k = 0; k < IN_F; k++) {
    float w = Wl[k * HID + j];
#pragma unroll
    for (int i = 0; i < 8; i++) acc[i] += xs[ng + 2 * i][k] * w;
  }
  float bb = b1[j];
#pragma unroll
  for (int i = 0; i < 8; i++) {
    float v = acc[i] + bb;
    v = v > 0.0f ? v : 0.0f;
    h1[(node0 + ng + 2 * i) * HID + j] = v;
  }
}

// ---------- transform-first for layer 2: g = h1 @ W2 (no bias) -------------
#define NB2 16
__global__ __launch_bounds__(256) void mm2_k(
    const float* __restrict__ h1, const float* __restrict__ W2,
    float* __restrict__ g) {
  __shared__ float W2l[HID * HID2];   // 32 KB
  __shared__ float xs[NB2][HID];      // 8 KB
  int t = threadIdx.x;
  for (int i = t; i < HID * HID2; i += 256) W2l[i] = W2[i];
  int node0 = blockIdx.x * NB2;
  for (int i = t; i < NB2 * HID; i += 256) {
    int n = i >> 7;
    int k = i & 127;
    xs[n][k] = h1[(node0 + n) * HID + k];
  }
  __syncthreads();
  int j = t & 63;    // output column (HID2)
  int ng = t >> 6;   // 0..3
  float acc[4];
#pragma unroll
  for (int i = 0; i < 4; i++) acc[i] = 0.0f;
  for (int k = 0; k < HID; k++) {
    float w = W2l[k * HID2 + j];
#pragma unroll
    for (int i = 0; i < 4; i++) acc[i] += xs[ng + 4 * i][k] * w;
  }
#pragma unroll
  for (int i = 0; i < 4; i++)
    g[(node0 + ng + 4 * i) * HID2 + j] = acc[i];
}

// ---------- layer 2 gather + head: out = relu(agg(g)/deg + b2) @ W3 + b3 ---
__global__ __launch_bounds__(256) void ghead_k(
    const float* __restrict__ g, const int* __restrict__ rowptr,
    const int* __restrict__ csr_src, const float* __restrict__ b2,
    const float* __restrict__ W3, const float* __restrict__ b3,
    float* __restrict__ out) {
  __shared__ float W3l[HID2 * NCLS];     // 2.5 KB
  __shared__ float hs[NB2][HID2 + 4];    // +4 keeps 16B alignment for float4
  int t = threadIdx.x;
  for (int i = t; i < HID2 * NCLS; i += 256) W3l[i] = W3[i];
  int node0 = blockIdx.x * NB2;
  int lane = t & 63;
  int wave = t >> 6;
  int eg = lane >> 4;
  int fc = lane & 15;
  const float4* gf4 = (const float4*)g;
  const float4* b2f4 = (const float4*)b2;
  for (int i = 0; i < 4; i++) {
    int ln = wave * 4 + i;
    int n = node0 + ln;
    int s = rowptr[n], e2 = rowptr[n + 1];
    float4 a = gatherrow_f4(gf4, csr_src, s, e2, eg, fc);
    int d = e2 - s;
    float inv = 1.0f / (d < 1 ? 1.0f : (float)d);
    if (eg == 0) {
      float4 bb = b2f4[fc];
      float4 v;
      v.x = a.x * inv + bb.x; v.y = a.y * inv + bb.y;
      v.z = a.z * inv + bb.z; v.w = a.w * inv + bb.w;
      v.x = v.x > 0.0f ? v.x : 0.0f;
      v.y = v.y > 0.0f ? v.y : 0.0f;
      v.z = v.z > 0.0f ? v.z : 0.0f;
      v.w = v.w > 0.0f ? v.w : 0.0f;
      *(float4*)&hs[ln][fc * 4] = v;
    }
  }
  __syncthreads();
  if (t < NB2 * NCLS) {
    int n = t / NCLS;
    int c = t - n * NCLS;
    float a = b3[c];
    for (int k = 0; k < HID2; k++) a += hs[n][k] * W3l[k * NCLS + c];
    out[(node0 + n) * NCLS + c] = a;
  }
}

extern "C" void kernel_launch(void* const* d_in, const int* in_sizes, int n_in,
                              void* d_out, int out_size, void* d_ws, size_t ws_size,
                              hipStream_t stream) {
  const float* x  = (const float*)d_in[0];
  const int*   ei = (const int*)d_in[1];
  const int*   row = ei;
  const int*   col = ei + N_EDGES;
  const float* W1 = (const float*)d_in[3];
  const float* b1 = (const float*)d_in[4];
  const float* W2 = (const float*)d_in[5];
  const float* b2 = (const float*)d_in[6];
  const float* W3 = (const float*)d_in[7];
  const float* b3 = (const float*)d_in[8];
  float* out = (float*)d_out;

  char* ws = (char*)d_ws;
  int*   rowptr  = (int*)ws;                            // 512 KB reserved
  int*   fillptr = (int*)(ws + (512 << 10));            // counts, then fill cursors
  int*   partials= (int*)(ws + (1 << 20));
  int*   pbase   = (int*)(ws + (1 << 20) + 512);
  int*   csr_src = (int*)(ws + (1 << 20) + 4096);       // 6.4 MB
  float* h1      = (float*)(ws + (8 << 20));            // 51.2 MB
  float* g       = h1 + (size_t)N_NODES * HID;          // 25.6 MB

  // ---- CSR build (XCD-local count + fill) ----
  hipMemsetAsync(fillptr, 0, N_NODES * sizeof(int), stream);
  count2_k<<<NRANGE * EBLK, 256, 0, stream>>>(col, fillptr);
  partial_k<<<NCHUNK, 256, 0, stream>>>(fillptr, partials);
  scanp_k<<<1, 1, 0, stream>>>(partials, pbase);
  rowptr_k<<<NCHUNK, 256, 0, stream>>>(fillptr, pbase, rowptr);
  hipMemcpyAsync(fillptr, rowptr, N_NODES * sizeof(int),
                 hipMemcpyDeviceToDevice, stream);
  fill2_k<<<NRANGE * EBLK, 256, 0, stream>>>(row, col, fillptr, csr_src);

  // ---- layer 1: gather + mm1 fused ----
  gmm1_k<<<N_NODES / NB1, 256, 0, stream>>>(x, rowptr, csr_src, W1, b1, h1);

  // ---- layer 2: transform-first, then gather + head fused ----
  mm2_k<<<N_NODES / NB2, 256, 0, stream>>>(h1, W2, g);
  ghead_k<<<N_NODES / NB2, 256, 0, stream>>>(g, rowptr, csr_src, b2, W3, b3, out);
}